// Round 1
// baseline (276.452 us; speedup 1.0000x reference)
//
#include <hip/hip_runtime.h>

// GAT attention weights (heads=1) for two block-diagonal graphs.
// Output = softmax-by-dst of leakyrelu(a_s[src]+a_d[dst]) over N*N edges.
//
// R6: recompute design. The old k3/k5 pair materialized ex (67 MB write +
// 67 MB read + 67 MB dst re-read) and spent ~55 us/CU-pair on divergent L1
// gathers of a_d (TA pipe, ~2 cyc/lane). Per m134/m136, random LDS *reads*
// are ~0.15 cyc/lane (5.8 cyc/wave-instr * ~1.6x conflicts) -- 13x cheaper
// than TA gathers. So:
//   kA_denom: stage a_s AND a_d in LDS; per edge 2 cheap LDS reads +
//             exp + 1 LDS atomic. No out write (only 8 MB partials).
//   kB_alpha: restage a_s/a_d/inv_denom in LDS; recompute ex (bitwise
//             identical inputs) and write alpha directly. 3 cheap LDS
//             reads/edge; streaming = 134 MB index re-read (L3-hot) +
//             67 MB coalesced out write.
// Zero divergent global gathers anywhere; ex never touches memory.
//
// No segment-max: logits bounded ~7.2 -> exp <= ~1400, safe in fp32.

#define NNODES 4096
#define NSEG   8192
#define NEG_SLOPE 0.2f
#define EK_TPB 1024
#define EK_QPB 8192          // int4 quads per edge-kernel block = 32768 edges

__global__ void k1_wvec(const float* __restrict__ W,
                        const float* __restrict__ att_src,
                        const float* __restrict__ att_dst,
                        float* __restrict__ wvs, float* __restrict__ wvd) {
    int f = threadIdx.x;
    const float* row = W + f * 128;
    float s = 0.f, d = 0.f;
    #pragma unroll 8
    for (int j = 0; j < 128; ++j) {
        float w = row[j];
        s += w * att_src[j];
        d += w * att_dst[j];
    }
    wvs[f] = s; wvd[f] = d;
}

__global__ void k2_logits(const float* __restrict__ x1, const float* __restrict__ x2,
                          const float* __restrict__ wvs, const float* __restrict__ wvd,
                          float* __restrict__ a_s, float* __restrict__ a_d) {
    int wave = blockIdx.x * 4 + (threadIdx.x >> 6);
    int lane = threadIdx.x & 63;
    const float* xrow = (wave < NNODES) ? (x1 + (size_t)wave * 256)
                                        : (x2 + (size_t)(wave - NNODES) * 256);
    float4 xv  = ((const float4*)xrow)[lane];
    float4 wsv = ((const float4*)wvs)[lane];
    float4 wdv = ((const float4*)wvd)[lane];
    float ps = xv.x*wsv.x + xv.y*wsv.y + xv.z*wsv.z + xv.w*wsv.w;
    float pd = xv.x*wdv.x + xv.y*wdv.y + xv.z*wdv.z + xv.w*wdv.w;
    #pragma unroll
    for (int o = 32; o > 0; o >>= 1) {
        ps += __shfl_down(ps, o);
        pd += __shfl_down(pd, o);
    }
    if (lane == 0) { a_s[wave] = ps; a_d[wave] = pd; }
}

__device__ __forceinline__ float lrelu_exp(float e) {
    e = (e > 0.f) ? e : NEG_SLOPE * e;
    return __expf(e);
}

// Pass 1: denominators only. 2 LDS reads + 1 LDS atomic per edge; no TA
// gathers; writes only per-block partials (8 MB total).
__global__ __launch_bounds__(EK_TPB) void kA_denom(
        const int* __restrict__ ei1, const int* __restrict__ ei2,
        const float* __restrict__ a_s, const float* __restrict__ a_d,
        float* __restrict__ partials, int E1, int g1_blocks) {
    __shared__ float las[NNODES];            // 16 KB
    __shared__ float lad[NNODES];            // 16 KB
    __shared__ float ssum[NNODES];           // 16 KB  (48 KB total -> 2 blk/CU by waves)
    int t = threadIdx.x;
    int b = blockIdx.x;
    const int* sp; int qbase, nodeoff;
    if (b < g1_blocks) { sp = ei1; qbase = b * EK_QPB; nodeoff = 0; }
    else { sp = ei2; qbase = (b - g1_blocks) * EK_QPB; nodeoff = NNODES; }
    const int4* s4 = (const int4*)sp;
    const int4* d4 = (const int4*)(sp + E1);

    // NNODES floats == 1024 float4 == exactly one pass of 1024 threads
    ((float4*)las)[t]  = ((const float4*)(a_s + nodeoff))[t];
    ((float4*)lad)[t]  = ((const float4*)(a_d + nodeoff))[t];
    ((float4*)ssum)[t] = make_float4(0.f, 0.f, 0.f, 0.f);
    __syncthreads();

    #pragma unroll
    for (int k = 0; k < 8; ++k) {
        int q = qbase + (k << 10) + t;
        int4 sv = s4[q];
        int4 dv = d4[q];
        float e0 = lrelu_exp(las[sv.x] + lad[dv.x]);
        float e1 = lrelu_exp(las[sv.y] + lad[dv.y]);
        float e2 = lrelu_exp(las[sv.z] + lad[dv.z]);
        float e3 = lrelu_exp(las[sv.w] + lad[dv.w]);
        atomicAdd(&ssum[dv.x], e0);
        atomicAdd(&ssum[dv.y], e1);
        atomicAdd(&ssum[dv.z], e2);
        atomicAdd(&ssum[dv.w], e3);
    }
    __syncthreads();
    float* pb = partials + (size_t)b * NNODES;
    ((float4*)pb)[t] = ((float4*)ssum)[t];
}

__global__ void k4a_reduce(const float* __restrict__ partials,
                           float* __restrict__ partials2, int g1_blocks) {
    int tid = blockIdx.x * blockDim.x + threadIdx.x;
    int c  = tid >> 13;
    int sg = tid & (NSEG - 1);
    int bpc = g1_blocks >> 3;
    int b0 = ((sg < NNODES) ? 0 : g1_blocks) + c * bpc;
    int col = sg & (NNODES - 1);
    float s = 0.f;
    for (int j = 0; j < bpc; ++j)
        s += partials[(size_t)(b0 + j) * NNODES + col];
    partials2[tid] = s;
}

__global__ void k4b_inv(const float* __restrict__ partials2,
                        float* __restrict__ inv_denom) {
    int sg = blockIdx.x * blockDim.x + threadIdx.x;
    float s = 0.f;
    #pragma unroll
    for (int c = 0; c < 8; ++c) s += partials2[c * NSEG + sg];
    inv_denom[sg] = 1.0f / s;
}

// Pass 2: recompute ex from LDS tables (identical fp ops as pass 1) and
// write alpha = ex * inv_denom[dst] directly. 3 LDS reads/edge, coalesced
// index reads (L3-hot) + coalesced out write. No ex round-trip.
__global__ __launch_bounds__(EK_TPB) void kB_alpha(
        const int* __restrict__ ei1, const int* __restrict__ ei2,
        const float* __restrict__ a_s, const float* __restrict__ a_d,
        const float* __restrict__ inv_denom,
        float* __restrict__ out, int E1, int g1_blocks) {
    __shared__ float las[NNODES];            // 16 KB
    __shared__ float lad[NNODES];            // 16 KB
    __shared__ float linv[NNODES];           // 16 KB
    int t = threadIdx.x;
    int b = blockIdx.x;
    const int* sp; int qbase, nodeoff, outq;
    if (b < g1_blocks) { sp = ei1; qbase = b * EK_QPB; nodeoff = 0; outq = qbase; }
    else { sp = ei2; qbase = (b - g1_blocks) * EK_QPB; nodeoff = NNODES; outq = E1/4 + qbase; }
    const int4* s4 = (const int4*)sp;
    const int4* d4 = (const int4*)(sp + E1);

    ((float4*)las)[t]  = ((const float4*)(a_s + nodeoff))[t];
    ((float4*)lad)[t]  = ((const float4*)(a_d + nodeoff))[t];
    ((float4*)linv)[t] = ((const float4*)(inv_denom + nodeoff))[t];
    __syncthreads();

    float4* out4 = (float4*)out;
    #pragma unroll
    for (int k = 0; k < 8; ++k) {
        int q = qbase + (k << 10) + t;
        int4 sv = s4[q];
        int4 dv = d4[q];
        float e0 = lrelu_exp(las[sv.x] + lad[dv.x]) * linv[dv.x];
        float e1 = lrelu_exp(las[sv.y] + lad[dv.y]) * linv[dv.y];
        float e2 = lrelu_exp(las[sv.z] + lad[dv.z]) * linv[dv.z];
        float e3 = lrelu_exp(las[sv.w] + lad[dv.w]) * linv[dv.w];
        out4[outq + (k << 10) + t] = make_float4(e0, e1, e2, e3);
    }
}

extern "C" void kernel_launch(void* const* d_in, const int* in_sizes, int n_in,
                              void* d_out, int out_size, void* d_ws, size_t ws_size,
                              hipStream_t stream) {
    const float* x1      = (const float*)d_in[0];
    const float* x2      = (const float*)d_in[1];
    const int*   ei1     = (const int*)d_in[2];
    const int*   ei2     = (const int*)d_in[3];
    const float* W       = (const float*)d_in[4];
    const float* att_src = (const float*)d_in[5];
    const float* att_dst = (const float*)d_in[6];
    float* out = (float*)d_out;

    const int E1 = in_sizes[2] / 2;          // 8388608 edges per graph

    float* wsf       = (float*)d_ws;
    float* wvs       = wsf;                  // 256
    float* wvd       = wsf + 256;            // 256
    float* a_s       = wsf + 512;            // 8192
    float* a_d       = wsf + 512 + NSEG;     // 8192
    float* inv_denom = wsf + 512 + 2*NSEG;   // 8192
    float* partials2 = wsf + 32768;          // 65536
    float* partials  = wsf + 131072;         // 512*4096 floats (8 MB)

    hipLaunchKernelGGL(k1_wvec, dim3(1), dim3(256), 0, stream,
                       W, att_src, att_dst, wvs, wvd);
    hipLaunchKernelGGL(k2_logits, dim3(2 * NNODES / 4), dim3(256), 0, stream,
                       x1, x2, wvs, wvd, a_s, a_d);

    int g1b = (E1 / 4) / EK_QPB;             // 256 blocks per graph half
    hipLaunchKernelGGL(kA_denom, dim3(2 * g1b), dim3(EK_TPB), 0, stream,
                       ei1, ei2, a_s, a_d, partials, E1, g1b);
    hipLaunchKernelGGL(k4a_reduce, dim3(8 * NSEG / 256), dim3(256), 0, stream,
                       partials, partials2, g1b);
    hipLaunchKernelGGL(k4b_inv, dim3(NSEG / 256), dim3(256), 0, stream,
                       partials2, inv_denom);
    hipLaunchKernelGGL(kB_alpha, dim3(2 * g1b), dim3(EK_TPB), 0, stream,
                       ei1, ei2, a_s, a_d, inv_denom, out, E1, g1b);
}

// Round 2
// 274.393 us; speedup vs baseline: 1.0075x; 1.0075x over previous
//
#include <hip/hip_runtime.h>

// GAT attention weights (heads=1) for two block-diagonal graphs.
// Output = softmax-by-dst of leakyrelu(a_s[src]+a_d[dst]) over N*N edges.
//
// R7: divergent-lane-op minimization. Measured model (k3 R5 vs kA R6):
// ANY divergent memory lane-op (random LDS read, LDS atomic, L1 gather)
// costs ~1.2 cyc/lane on a shared per-CU resource; 3 ops/edge == ~97 us.
// Pass 1 floor is 3 ops/edge (src read, dst threshold read, dst atomic --
// the lrelu kink forces the per-edge branch). Pass 2 drops 3 -> 1 op:
//   exp(lrelu(as+ad)) = e^as * e^ad          (as+ad > 0)
//                     = e^{.2as} * e^{.2ad}  (else)
// Pass 1 streams val = branch ? +e^as : -e^{.2as} into d_out (write pipe
// measured free) and accumulates split sums s1,s2 per dst. Pass 2 reads
// val + dst, does ONE ds_read_b64 of {u=e^ad*inv, v=e^{.2ad}*inv}:
//   alpha = val>0 ? val*u : (-val)*v.
// Branch is decided once (p > e^{-ad}, bitwise-identical tables) and
// carried in val's sign bit. No exp, no src read in pass 2.
//
// No segment-max: logits bounded ~7.2 -> exp <= ~1400, safe in fp32.

#define NNODES 4096
#define NSEG   8192
#define NEG_SLOPE 0.2f
#define EK_TPB 1024
#define EK_QPB 8192          // int4 quads per edge-kernel block = 32768 edges

__global__ void k1_wvec(const float* __restrict__ W,
                        const float* __restrict__ att_src,
                        const float* __restrict__ att_dst,
                        float* __restrict__ wvs, float* __restrict__ wvd) {
    int f = threadIdx.x;
    const float* row = W + f * 128;
    float s = 0.f, d = 0.f;
    #pragma unroll 8
    for (int j = 0; j < 128; ++j) {
        float w = row[j];
        s += w * att_src[j];
        d += w * att_dst[j];
    }
    wvs[f] = s; wvd[f] = d;
}

// Per-node logits + precomputed tables:
//   espair[n] = {e^{a_s}, e^{0.2 a_s}}   (pass-1 src operand, one b64 read)
//   wtab[n]   = e^{-a_d}                 (pass-1 branch threshold: p > w)
//   a_d[n]                               (kA epilogue / k4b combine)
__global__ void k2_logits(const float* __restrict__ x1, const float* __restrict__ x2,
                          const float* __restrict__ wvs, const float* __restrict__ wvd,
                          float* __restrict__ a_d, float2* __restrict__ espair,
                          float* __restrict__ wtab) {
    int wave = blockIdx.x * 4 + (threadIdx.x >> 6);
    int lane = threadIdx.x & 63;
    const float* xrow = (wave < NNODES) ? (x1 + (size_t)wave * 256)
                                        : (x2 + (size_t)(wave - NNODES) * 256);
    float4 xv  = ((const float4*)xrow)[lane];
    float4 wsv = ((const float4*)wvs)[lane];
    float4 wdv = ((const float4*)wvd)[lane];
    float ps = xv.x*wsv.x + xv.y*wsv.y + xv.z*wsv.z + xv.w*wsv.w;
    float pd = xv.x*wdv.x + xv.y*wdv.y + xv.z*wdv.z + xv.w*wdv.w;
    #pragma unroll
    for (int o = 32; o > 0; o >>= 1) {
        ps += __shfl_down(ps, o);
        pd += __shfl_down(pd, o);
    }
    if (lane == 0) {
        a_d[wave]    = pd;
        espair[wave] = make_float2(__expf(ps), __expf(NEG_SLOPE * ps));
        wtab[wave]   = __expf(-pd);
    }
}

// Pass 1: 3 divergent ops/edge (b64 src-pair read, b32 threshold read,
// b32 atomic into s12[dst or dst+NNODES]). Streams signed val to d_out.
// Epilogue folds {s1,s2} into a single per-block partial denominator.
__global__ __launch_bounds__(EK_TPB) void kA_denom(
        const int* __restrict__ ei1, const int* __restrict__ ei2,
        const float2* __restrict__ espair, const float* __restrict__ wtab,
        const float* __restrict__ a_d,
        float* __restrict__ partials, float* __restrict__ out,
        int E1, int g1_blocks) {
    __shared__ float2 les[NNODES];           // 32 KB {e^as, e^.2as}
    __shared__ float  lw[NNODES];            // 16 KB e^{-ad}
    __shared__ float  s12[2 * NNODES];       // 32 KB split sums (80 KB total -> 2 blk/CU)
    int t = threadIdx.x;
    int b = blockIdx.x;
    const int* sp; int qbase, nodeoff, outq;
    if (b < g1_blocks) { sp = ei1; qbase = b * EK_QPB; nodeoff = 0; outq = qbase; }
    else { sp = ei2; qbase = (b - g1_blocks) * EK_QPB; nodeoff = NNODES; outq = E1/4 + qbase; }
    const int4* s4 = (const int4*)sp;
    const int4* d4 = (const int4*)(sp + E1);

    {   // stage: les = 2048 float4, lw = 1024 float4, s12 = 2048 float4
        float4* lesv = (float4*)les;
        const float4* gesv = (const float4*)(espair + nodeoff);
        lesv[t] = gesv[t]; lesv[t + 1024] = gesv[t + 1024];
        ((float4*)lw)[t] = ((const float4*)(wtab + nodeoff))[t];
        float4* sv = (float4*)s12;
        sv[t] = make_float4(0.f,0.f,0.f,0.f);
        sv[t + 1024] = make_float4(0.f,0.f,0.f,0.f);
    }
    __syncthreads();

    float4* out4 = (float4*)out;
    #pragma unroll
    for (int k = 0; k < 8; ++k) {
        int q = qbase + (k << 10) + t;
        int4 sv = s4[q];
        int4 dv = d4[q];
        float2 e0 = les[sv.x], e1 = les[sv.y], e2 = les[sv.z], e3 = les[sv.w];
        float  w0 = lw[dv.x],  w1 = lw[dv.y],  w2 = lw[dv.z],  w3 = lw[dv.w];
        bool p0 = e0.x > w0, p1 = e1.x > w1, p2 = e2.x > w2, p3 = e3.x > w3;
        atomicAdd(&s12[dv.x + (p0 ? 0 : NNODES)], p0 ? e0.x : e0.y);
        atomicAdd(&s12[dv.y + (p1 ? 0 : NNODES)], p1 ? e1.x : e1.y);
        atomicAdd(&s12[dv.z + (p2 ? 0 : NNODES)], p2 ? e2.x : e2.y);
        atomicAdd(&s12[dv.w + (p3 ? 0 : NNODES)], p3 ? e3.x : e3.y);
        out4[outq + (k << 10) + t] = make_float4(p0 ? e0.x : -e0.y,
                                                 p1 ? e1.x : -e1.y,
                                                 p2 ? e2.x : -e2.y,
                                                 p3 ? e3.x : -e3.y);
    }
    __syncthreads();

    // partial_denom[n] = e^{ad}*s1[n] + e^{0.2 ad}*s2[n]  (linear in s1,s2,
    // so per-block combine is exact); keeps partials at 8 MB total.
    float4 ad4 = ((const float4*)(a_d + nodeoff))[t];
    int n = 4 * t;
    float4 r;
    r.x = __expf(ad4.x) * s12[n+0] + __expf(NEG_SLOPE * ad4.x) * s12[n+0+NNODES];
    r.y = __expf(ad4.y) * s12[n+1] + __expf(NEG_SLOPE * ad4.y) * s12[n+1+NNODES];
    r.z = __expf(ad4.z) * s12[n+2] + __expf(NEG_SLOPE * ad4.z) * s12[n+2+NNODES];
    r.w = __expf(ad4.w) * s12[n+3] + __expf(NEG_SLOPE * ad4.w) * s12[n+3+NNODES];
    ((float4*)(partials + (size_t)b * NNODES))[t] = r;
}

__global__ void k4a_reduce(const float* __restrict__ partials,
                           float* __restrict__ partials2, int g1_blocks) {
    int tid = blockIdx.x * blockDim.x + threadIdx.x;
    int c  = tid >> 13;
    int sg = tid & (NSEG - 1);
    int bpc = g1_blocks >> 3;
    int b0 = ((sg < NNODES) ? 0 : g1_blocks) + c * bpc;
    int col = sg & (NNODES - 1);
    float s = 0.f;
    for (int j = 0; j < bpc; ++j)
        s += partials[(size_t)(b0 + j) * NNODES + col];
    partials2[tid] = s;
}

__global__ void k4b_inv(const float* __restrict__ partials2,
                        const float* __restrict__ a_d,
                        float2* __restrict__ uv) {
    int sg = blockIdx.x * blockDim.x + threadIdx.x;
    float s = 0.f;
    #pragma unroll
    for (int c = 0; c < 8; ++c) s += partials2[c * NSEG + sg];
    float inv = 1.0f / s;
    float ad = a_d[sg];
    uv[sg] = make_float2(__expf(ad) * inv, __expf(NEG_SLOPE * ad) * inv);
}

// Pass 2: ONE divergent op/edge (ds_read_b64 of {u,v} by dst). val sign
// carries the pass-1 branch. Streaming: val in, dst in, alpha out.
__global__ __launch_bounds__(EK_TPB) void kB_alpha(
        const int* __restrict__ ei1, const int* __restrict__ ei2,
        const float2* __restrict__ uv,
        float* __restrict__ out, int E1, int g1_blocks) {
    __shared__ float2 luv[NNODES];           // 32 KB
    int t = threadIdx.x;
    int b = blockIdx.x;
    const int* sp; int qbase, outq;
    const float2* uvg;
    if (b < g1_blocks) { sp = ei1; qbase = b * EK_QPB; uvg = uv; outq = qbase; }
    else { sp = ei2; qbase = (b - g1_blocks) * EK_QPB; uvg = uv + NNODES; outq = E1/4 + qbase; }
    const int4* d4 = (const int4*)(sp + E1);

    float4* luvv = (float4*)luv;
    const float4* guv = (const float4*)uvg;
    luvv[t] = guv[t]; luvv[t + 1024] = guv[t + 1024];
    __syncthreads();

    float4* out4 = (float4*)out;
    #pragma unroll
    for (int k = 0; k < 8; ++k) {
        int q = qbase + (k << 10) + t;
        int4   dv  = d4[q];
        float4 val = out4[outq + (k << 10) + t];
        float2 u0 = luv[dv.x], u1 = luv[dv.y], u2 = luv[dv.z], u3 = luv[dv.w];
        val.x = (val.x > 0.f) ? val.x * u0.x : (-val.x) * u0.y;
        val.y = (val.y > 0.f) ? val.y * u1.x : (-val.y) * u1.y;
        val.z = (val.z > 0.f) ? val.z * u2.x : (-val.z) * u2.y;
        val.w = (val.w > 0.f) ? val.w * u3.x : (-val.w) * u3.y;
        out4[outq + (k << 10) + t] = val;
    }
}

extern "C" void kernel_launch(void* const* d_in, const int* in_sizes, int n_in,
                              void* d_out, int out_size, void* d_ws, size_t ws_size,
                              hipStream_t stream) {
    const float* x1      = (const float*)d_in[0];
    const float* x2      = (const float*)d_in[1];
    const int*   ei1     = (const int*)d_in[2];
    const int*   ei2     = (const int*)d_in[3];
    const float* W       = (const float*)d_in[4];
    const float* att_src = (const float*)d_in[5];
    const float* att_dst = (const float*)d_in[6];
    float* out = (float*)d_out;

    const int E1 = in_sizes[2] / 2;          // 8388608 edges per graph

    float* wsf       = (float*)d_ws;
    float* wvs       = wsf;                  // 256
    float* wvd       = wsf + 256;            // 256
    float* a_d       = wsf + 512;            // 8192
    float2* espair   = (float2*)(wsf + 512 + NSEG);        // 8192 float2 (16384 f)
    float* wtab      = wsf + 512 + NSEG + 2*NSEG;          // 8192
    float2* uv       = (float2*)(wsf + 512 + 4*NSEG);      // 8192 float2 (16384 f)
    float* partials2 = wsf + 65536;          // 8*8192 = 65536 floats
    float* partials  = wsf + 131072;         // 512*4096 floats (8 MB)

    hipLaunchKernelGGL(k1_wvec, dim3(1), dim3(256), 0, stream,
                       W, att_src, att_dst, wvs, wvd);
    hipLaunchKernelGGL(k2_logits, dim3(2 * NNODES / 4), dim3(256), 0, stream,
                       x1, x2, wvs, wvd, a_d, espair, wtab);

    int g1b = (E1 / 4) / EK_QPB;             // 256 blocks per graph half
    hipLaunchKernelGGL(kA_denom, dim3(2 * g1b), dim3(EK_TPB), 0, stream,
                       ei1, ei2, espair, wtab, a_d, partials, out, E1, g1b);
    hipLaunchKernelGGL(k4a_reduce, dim3(8 * NSEG / 256), dim3(256), 0, stream,
                       partials, partials2, g1b);
    hipLaunchKernelGGL(k4b_inv, dim3(NSEG / 256), dim3(256), 0, stream,
                       partials2, a_d, uv);
    hipLaunchKernelGGL(kB_alpha, dim3(2 * g1b), dim3(EK_TPB), 0, stream,
                       ei1, ei2, uv, out, E1, g1b);
}